// Round 1
// baseline (782.494 us; speedup 1.0000x reference)
//
#include <hip/hip_runtime.h>

constexpr int C = 768;
constexpr int NPATCH = 1024;   // (448/14)^2
constexpr int H = 448, W = 448;
constexpr int HW = H * W;      // 200704
constexpr int TOPK = 200;      // int(200704 * 0.001)
constexpr float EPS = 1e-12f;

__device__ __forceinline__ float dot4(const float4 a, const float4 b) {
    return a.x * b.x + a.y * b.y + a.z * b.z + a.w * b.w;
}

// One wave (64 lanes) per (b, n) row: computes
// combined = ||norm(pm)-norm(m)||_2 * ||norm(pl)-norm(l)||_2
__global__ __launch_bounds__(256) void anom_kernel(
    const float* __restrict__ m, const float* __restrict__ l,
    const float* __restrict__ pm, const float* __restrict__ pl,
    float* __restrict__ combined, int rows) {
    int wid = (int)((blockIdx.x * blockDim.x + threadIdx.x) >> 6);
    int lane = threadIdx.x & 63;
    if (wid >= rows) return;
    size_t base = (size_t)wid * C;
    const float4* m4 = (const float4*)(m + base);
    const float4* l4 = (const float4*)(l + base);
    const float4* pm4 = (const float4*)(pm + base);
    const float4* pl4 = (const float4*)(pl + base);

    float4 vm[3], vl[3], vpm[3], vpl[3];
    float sm = 0.f, sl = 0.f, spm = 0.f, spl = 0.f;
#pragma unroll
    for (int j = 0; j < 3; ++j) {
        vm[j] = m4[lane + 64 * j];
        vl[j] = l4[lane + 64 * j];
        vpm[j] = pm4[lane + 64 * j];
        vpl[j] = pl4[lane + 64 * j];
        sm += dot4(vm[j], vm[j]);
        sl += dot4(vl[j], vl[j]);
        spm += dot4(vpm[j], vpm[j]);
        spl += dot4(vpl[j], vpl[j]);
    }
#pragma unroll
    for (int off = 32; off > 0; off >>= 1) {
        sm += __shfl_xor(sm, off);
        sl += __shfl_xor(sl, off);
        spm += __shfl_xor(spm, off);
        spl += __shfl_xor(spl, off);
    }
    float rm = 1.0f / fmaxf(sqrtf(sm), EPS);
    float rl = 1.0f / fmaxf(sqrtf(sl), EPS);
    float rpm = 1.0f / fmaxf(sqrtf(spm), EPS);
    float rpl = 1.0f / fmaxf(sqrtf(spl), EPS);

    float dm = 0.f, dl = 0.f;
#pragma unroll
    for (int j = 0; j < 3; ++j) {
        float d;
        d = vpm[j].x * rpm - vm[j].x * rm; dm += d * d;
        d = vpm[j].y * rpm - vm[j].y * rm; dm += d * d;
        d = vpm[j].z * rpm - vm[j].z * rm; dm += d * d;
        d = vpm[j].w * rpm - vm[j].w * rm; dm += d * d;
        d = vpl[j].x * rpl - vl[j].x * rl; dl += d * d;
        d = vpl[j].y * rpl - vl[j].y * rl; dl += d * d;
        d = vpl[j].z * rpl - vl[j].z * rl; dl += d * d;
        d = vpl[j].w * rpl - vl[j].w * rl; dl += d * d;
    }
#pragma unroll
    for (int off = 32; off > 0; off >>= 1) {
        dm += __shfl_xor(dm, off);
        dl += __shfl_xor(dl, off);
    }
    if (lane == 0) combined[wid] = sqrtf(dm) * sqrtf(dl);
}

// Half-pixel-center bilinear upsample (B,32,32) -> (B,448,448).
// Edge renormalization in jax.image.resize == index clamping here.
__global__ __launch_bounds__(256) void upsample_kernel(
    const float* __restrict__ src, float* __restrict__ dst, int total) {
    int idx = blockIdx.x * blockDim.x + threadIdx.x;
    if (idx >= total) return;
    int x = idx % W;
    int y = (idx / W) % H;
    int b = idx / HW;
    float sx = (x + 0.5f) * (1.0f / 14.0f) - 0.5f;
    float sy = (y + 0.5f) * (1.0f / 14.0f) - 0.5f;
    float fx0 = floorf(sx), fy0 = floorf(sy);
    float fx = sx - fx0, fy = sy - fy0;
    int x0 = (int)fx0, y0 = (int)fy0;
    int x0c = min(max(x0, 0), 31);
    int x1c = min(max(x0 + 1, 0), 31);
    int y0c = min(max(y0, 0), 31);
    int y1c = min(max(y0 + 1, 0), 31);
    const float* s = src + (size_t)b * NPATCH;
    float v00 = s[y0c * 32 + x0c], v01 = s[y0c * 32 + x1c];
    float v10 = s[y1c * 32 + x0c], v11 = s[y1c * 32 + x1c];
    float v = (1.f - fy) * ((1.f - fx) * v00 + fx * v01) +
              fy * ((1.f - fx) * v10 + fx * v11);
    dst[idx] = v;
}

// One box-blur pass (zero padding, same-size), separable H then V in LDS.
// Tile 64x64 output, halo P. 448 = 7*64 exactly.
template <int P>
__global__ __launch_bounds__(256) void blur_kernel(
    const float* __restrict__ src, float* __restrict__ dst) {
    constexpr int T = 64;
    constexpr int S = T + 2 * P;
    constexpr float inv = 1.0f / (2 * P + 1);
    __shared__ float tin[S][S];
    __shared__ float tmp[S][T];

    int tilex = blockIdx.x % 7;
    int tiley = (blockIdx.x / 7) % 7;
    int b = blockIdx.x / 49;
    int ox0 = tilex * T, oy0 = tiley * T;
    const float* s = src + (size_t)b * HW;
    float* d = dst + (size_t)b * HW;

    for (int i = threadIdx.x; i < S * S; i += 256) {
        int r = i / S, c = i % S;
        int gy = oy0 + r - P, gx = ox0 + c - P;
        float v = 0.f;
        if (gy >= 0 && gy < H && gx >= 0 && gx < W) v = s[gy * W + gx];
        tin[r][c] = v;
    }
    __syncthreads();
    for (int i = threadIdx.x; i < S * T; i += 256) {
        int r = i / T, c = i % T;
        float a = 0.f;
#pragma unroll
        for (int j = 0; j <= 2 * P; ++j) a += tin[r][c + j];
        tmp[r][c] = a * inv;
    }
    __syncthreads();
    for (int i = threadIdx.x; i < T * T; i += 256) {
        int r = i / T, c = i % T;
        float a = 0.f;
#pragma unroll
        for (int j = 0; j <= 2 * P; ++j) a += tmp[r + j][c];
        d[(size_t)(oy0 + r) * W + (ox0 + c)] = a * inv;
    }
}

// Exact top-200 mean per batch via 8-bit radix select on float bits.
// All map values are >= 0, so uint32 bit order == float order.
__global__ __launch_bounds__(256) void topk_kernel(
    const float* __restrict__ map, float* __restrict__ score) {
    int b = blockIdx.x;
    const float* s = map + (size_t)b * HW;
    const unsigned* u = (const unsigned*)s;
    __shared__ unsigned hist[256];
    __shared__ unsigned sh_prefix;
    __shared__ int sh_k;
    int tid = threadIdx.x;

    unsigned prefix = 0;
    int k = TOPK;
    for (int dgt = 3; dgt >= 0; --dgt) {
        hist[tid] = 0;
        __syncthreads();
        for (int i = tid; i < HW; i += 256) {
            unsigned v = u[i];
            bool match;
            if (dgt == 3) match = true;
            else match = ((v >> (8 * (dgt + 1))) == prefix);
            if (match) atomicAdd(&hist[(v >> (8 * dgt)) & 255u], 1u);
        }
        __syncthreads();
        if (tid == 0) {
            int acc = 0;
            int j = 255;
            for (; j >= 0; --j) {
                acc += (int)hist[j];
                if (acc >= k) break;
            }
            sh_k = k - (acc - (int)hist[j]);
            sh_prefix = (prefix << 8) | (unsigned)j;
        }
        __syncthreads();
        prefix = sh_prefix;
        k = sh_k;
        __syncthreads();
    }

    float thr = __uint_as_float(prefix);
    float sum = 0.f;
    int cnt = 0;
    for (int i = tid; i < HW; i += 256) {
        float v = s[i];
        if (v > thr) { sum += v; cnt++; }
    }
#pragma unroll
    for (int off = 32; off > 0; off >>= 1) {
        sum += __shfl_xor(sum, off);
        cnt += __shfl_xor(cnt, off);
    }
    __shared__ float wsum[4];
    __shared__ int wcnt[4];
    int wv = tid >> 6;
    if ((tid & 63) == 0) { wsum[wv] = sum; wcnt[wv] = cnt; }
    __syncthreads();
    if (tid == 0) {
        float s2 = 0.f;
        int c2 = 0;
        for (int i = 0; i < 4; ++i) { s2 += wsum[i]; c2 += wcnt[i]; }
        score[b] = (s2 + (float)(TOPK - c2) * thr) * (1.0f / TOPK);
    }
}

extern "C" void kernel_launch(void* const* d_in, const int* in_sizes, int n_in,
                              void* d_out, int out_size, void* d_ws, size_t ws_size,
                              hipStream_t stream) {
    const float* mid = (const float*)d_in[0];
    const float* last = (const float*)d_in[1];
    const float* pmid = (const float*)d_in[2];
    const float* plast = (const float*)d_in[3];
    int B = in_sizes[0] / (NPATCH * C);  // 16

    float* out_map = (float*)d_out;                     // B*448*448
    float* out_score = out_map + (size_t)B * HW;        // B
    float* combined = (float*)d_ws;                     // B*1024
    float* bufA = combined + (size_t)B * NPATCH;        // B*448*448

    int rows = B * NPATCH;
    anom_kernel<<<(rows + 3) / 4, 256, 0, stream>>>(mid, last, pmid, plast,
                                                    combined, rows);
    int total = B * HW;
    upsample_kernel<<<(total + 255) / 256, 256, 0, stream>>>(combined, out_map,
                                                             total);
    int nblk = B * 49;
    // 5x (5x5, pad 2) then 3x (7x7, pad 3); parity ends in d_out.
    blur_kernel<2><<<nblk, 256, 0, stream>>>(out_map, bufA);
    blur_kernel<2><<<nblk, 256, 0, stream>>>(bufA, out_map);
    blur_kernel<2><<<nblk, 256, 0, stream>>>(out_map, bufA);
    blur_kernel<2><<<nblk, 256, 0, stream>>>(bufA, out_map);
    blur_kernel<2><<<nblk, 256, 0, stream>>>(out_map, bufA);
    blur_kernel<3><<<nblk, 256, 0, stream>>>(bufA, out_map);
    blur_kernel<3><<<nblk, 256, 0, stream>>>(out_map, bufA);
    blur_kernel<3><<<nblk, 256, 0, stream>>>(bufA, out_map);

    topk_kernel<<<B, 256, 0, stream>>>(out_map, out_score);
}

// Round 2
// 335.886 us; speedup vs baseline: 2.3296x; 2.3296x over previous
//
#include <hip/hip_runtime.h>

constexpr int C = 768;
constexpr int NPATCH = 1024;   // (448/14)^2
constexpr int H = 448, W = 448;
constexpr int HW = H * W;      // 200704
constexpr int TOPK = 200;      // int(200704 * 0.001)
constexpr float EPS = 1e-12f;

constexpr int HBITS = 13;
constexpr int HBINS = 1 << HBITS;   // 8192
constexpr int HSHIFT = 18;          // bin = float_bits >> 18 (sign always 0)
constexpr int SLICES = 16;          // hist blocks per batch

__device__ __forceinline__ float dot4(const float4 a, const float4 b) {
    return a.x * b.x + a.y * b.y + a.z * b.z + a.w * b.w;
}

// One wave (64 lanes) per (b, n) row: computes
// combined = ||norm(pm)-norm(m)||_2 * ||norm(pl)-norm(l)||_2
__global__ __launch_bounds__(256) void anom_kernel(
    const float* __restrict__ m, const float* __restrict__ l,
    const float* __restrict__ pm, const float* __restrict__ pl,
    float* __restrict__ combined, int rows) {
    int wid = (int)((blockIdx.x * blockDim.x + threadIdx.x) >> 6);
    int lane = threadIdx.x & 63;
    if (wid >= rows) return;
    size_t base = (size_t)wid * C;
    const float4* m4 = (const float4*)(m + base);
    const float4* l4 = (const float4*)(l + base);
    const float4* pm4 = (const float4*)(pm + base);
    const float4* pl4 = (const float4*)(pl + base);

    float4 vm[3], vl[3], vpm[3], vpl[3];
    float sm = 0.f, sl = 0.f, spm = 0.f, spl = 0.f;
#pragma unroll
    for (int j = 0; j < 3; ++j) {
        vm[j] = m4[lane + 64 * j];
        vl[j] = l4[lane + 64 * j];
        vpm[j] = pm4[lane + 64 * j];
        vpl[j] = pl4[lane + 64 * j];
        sm += dot4(vm[j], vm[j]);
        sl += dot4(vl[j], vl[j]);
        spm += dot4(vpm[j], vpm[j]);
        spl += dot4(vpl[j], vpl[j]);
    }
#pragma unroll
    for (int off = 32; off > 0; off >>= 1) {
        sm += __shfl_xor(sm, off);
        sl += __shfl_xor(sl, off);
        spm += __shfl_xor(spm, off);
        spl += __shfl_xor(spl, off);
    }
    float rm = 1.0f / fmaxf(sqrtf(sm), EPS);
    float rl = 1.0f / fmaxf(sqrtf(sl), EPS);
    float rpm = 1.0f / fmaxf(sqrtf(spm), EPS);
    float rpl = 1.0f / fmaxf(sqrtf(spl), EPS);

    float dm = 0.f, dl = 0.f;
#pragma unroll
    for (int j = 0; j < 3; ++j) {
        float d;
        d = vpm[j].x * rpm - vm[j].x * rm; dm += d * d;
        d = vpm[j].y * rpm - vm[j].y * rm; dm += d * d;
        d = vpm[j].z * rpm - vm[j].z * rm; dm += d * d;
        d = vpm[j].w * rpm - vm[j].w * rm; dm += d * d;
        d = vpl[j].x * rpl - vl[j].x * rl; dl += d * d;
        d = vpl[j].y * rpl - vl[j].y * rl; dl += d * d;
        d = vpl[j].z * rpl - vl[j].z * rl; dl += d * d;
        d = vpl[j].w * rpl - vl[j].w * rl; dl += d * d;
    }
#pragma unroll
    for (int off = 32; off > 0; off >>= 1) {
        dm += __shfl_xor(dm, off);
        dl += __shfl_xor(dl, off);
    }
    if (lane == 0) combined[wid] = sqrtf(dm) * sqrtf(dl);
}

// Half-pixel-center bilinear upsample (B,32,32) -> (B,448,448).
__global__ __launch_bounds__(256) void upsample_kernel(
    const float* __restrict__ src, float* __restrict__ dst, int total) {
    int idx = blockIdx.x * blockDim.x + threadIdx.x;
    if (idx >= total) return;
    int x = idx % W;
    int y = (idx / W) % H;
    int b = idx / HW;
    float sx = (x + 0.5f) * (1.0f / 14.0f) - 0.5f;
    float sy = (y + 0.5f) * (1.0f / 14.0f) - 0.5f;
    float fx0 = floorf(sx), fy0 = floorf(sy);
    float fx = sx - fx0, fy = sy - fy0;
    int x0 = (int)fx0, y0 = (int)fy0;
    int x0c = min(max(x0, 0), 31);
    int x1c = min(max(x0 + 1, 0), 31);
    int y0c = min(max(y0, 0), 31);
    int y1c = min(max(y0 + 1, 0), 31);
    const float* s = src + (size_t)b * NPATCH;
    float v00 = s[y0c * 32 + x0c], v01 = s[y0c * 32 + x1c];
    float v10 = s[y1c * 32 + x0c], v11 = s[y1c * 32 + x1c];
    float v = (1.f - fy) * ((1.f - fx) * v00 + fx * v01) +
              fy * ((1.f - fx) * v10 + fx * v11);
    dst[idx] = v;
}

// One box-blur pass (zero padding, same-size), separable H then V in LDS.
template <int P>
__global__ __launch_bounds__(256) void blur_kernel(
    const float* __restrict__ src, float* __restrict__ dst) {
    constexpr int T = 64;
    constexpr int S = T + 2 * P;
    constexpr float inv = 1.0f / (2 * P + 1);
    __shared__ float tin[S][S];
    __shared__ float tmp[S][T];

    int tilex = blockIdx.x % 7;
    int tiley = (blockIdx.x / 7) % 7;
    int b = blockIdx.x / 49;
    int ox0 = tilex * T, oy0 = tiley * T;
    const float* s = src + (size_t)b * HW;
    float* d = dst + (size_t)b * HW;

    for (int i = threadIdx.x; i < S * S; i += 256) {
        int r = i / S, c = i % S;
        int gy = oy0 + r - P, gx = ox0 + c - P;
        float v = 0.f;
        if (gy >= 0 && gy < H && gx >= 0 && gx < W) v = s[gy * W + gx];
        tin[r][c] = v;
    }
    __syncthreads();
    for (int i = threadIdx.x; i < S * T; i += 256) {
        int r = i / T, c = i % T;
        float a = 0.f;
#pragma unroll
        for (int j = 0; j <= 2 * P; ++j) a += tin[r][c + j];
        tmp[r][c] = a * inv;
    }
    __syncthreads();
    for (int i = threadIdx.x; i < T * T; i += 256) {
        int r = i / T, c = i % T;
        float a = 0.f;
#pragma unroll
        for (int j = 0; j <= 2 * P; ++j) a += tmp[r + j][c];
        d[(size_t)(oy0 + r) * W + (ox0 + c)] = a * inv;
    }
}

// ---------------- grid-parallel exact top-k ----------------

__global__ __launch_bounds__(256) void zero_kernel(unsigned* __restrict__ hist,
                                                   int* __restrict__ ccount,
                                                   int nh, int nb) {
    int i = blockIdx.x * blockDim.x + threadIdx.x;
    if (i < nh) hist[i] = 0;
    if (i < nb) ccount[i] = 0;
}

// Per-batch 8192-bin histogram of top-13 float bits.
__global__ __launch_bounds__(256) void hist_kernel(
    const float* __restrict__ map, unsigned* __restrict__ hist) {
    __shared__ unsigned lh[HBINS];
    int b = blockIdx.x / SLICES, sl = blockIdx.x % SLICES;
    for (int i = threadIdx.x; i < HBINS; i += 256) lh[i] = 0;
    __syncthreads();
    const unsigned* u = (const unsigned*)(map + (size_t)b * HW);
    int per = HW / SLICES;  // 12544
    int start = sl * per;
    for (int i = start + threadIdx.x; i < start + per; i += 256)
        atomicAdd(&lh[u[i] >> HSHIFT], 1u);
    __syncthreads();
    unsigned* gh = hist + (size_t)b * HBINS;
    for (int i = threadIdx.x; i < HBINS; i += 256) {
        unsigned c = lh[i];
        if (c) atomicAdd(&gh[i], c);
    }
}

// Per batch: find bin such that count(bins > selbin) < TOPK <= count(bins >= selbin).
__global__ __launch_bounds__(256) void select_kernel(
    const unsigned* __restrict__ hist, int* __restrict__ selbin) {
    int b = blockIdx.x;
    const unsigned* gh = hist + (size_t)b * HBINS;
    constexpr int CHUNK = HBINS / 256;  // 32
    __shared__ unsigned csum[256];
    int tid = threadIdx.x;
    unsigned s = 0;
#pragma unroll
    for (int j = 0; j < CHUNK; ++j) s += gh[tid * CHUNK + j];
    csum[tid] = s;
    __syncthreads();
    if (tid == 0) {
        unsigned acc = 0;
        int t = 255;
        for (; t > 0; --t) {
            if (acc + csum[t] >= TOPK) break;
            acc += csum[t];
        }
        int base = t * CHUNK;
        int j = CHUNK - 1;
        for (; j > 0; --j) {
            unsigned c = gh[base + j];
            if (acc + c >= TOPK) break;
            acc += c;
        }
        selbin[b] = base + j;
    }
}

// Append all values with bin >= selbin[b] to cand[b*HW ...] (wave-aggregated).
__global__ __launch_bounds__(256) void compact_kernel(
    const float* __restrict__ map, const int* __restrict__ selbin,
    int* __restrict__ ccount, float* __restrict__ cand) {
    int idx = blockIdx.x * blockDim.x + threadIdx.x;
    if (idx >= 16 * HW) return;  // grid exact anyway
    int b = idx / HW;
    unsigned v = ((const unsigned*)map)[idx];
    bool take = (int)(v >> HSHIFT) >= selbin[b];
    unsigned long long mask = __ballot(take);
    if (mask == 0ull) return;
    int lane = threadIdx.x & 63;
    int n = __popcll(mask);
    int leader = __ffsll((unsigned long long)mask) - 1;
    int base = 0;
    if (lane == leader) base = atomicAdd(&ccount[b], n);
    base = __shfl(base, leader);
    if (take) {
        int pos = base + __popcll(mask & ((1ull << lane) - 1ull));
        cand[(size_t)b * HW + pos] = __uint_as_float(v);
    }
}

// Exact top-200 mean per batch via radix select over the candidate set.
__global__ __launch_bounds__(256) void topk_kernel(
    const float* __restrict__ cand, const int* __restrict__ ccount,
    float* __restrict__ score) {
    int b = blockIdx.x;
    const float* s = cand + (size_t)b * HW;
    const unsigned* u = (const unsigned*)s;
    int M = ccount[b];
    __shared__ unsigned hist[256];
    __shared__ unsigned sh_prefix;
    __shared__ int sh_k;
    int tid = threadIdx.x;

    unsigned prefix = 0;
    int k = TOPK;
    for (int dgt = 3; dgt >= 0; --dgt) {
        hist[tid] = 0;
        __syncthreads();
        for (int i = tid; i < M; i += 256) {
            unsigned v = u[i];
            bool match;
            if (dgt == 3) match = true;
            else match = ((v >> (8 * (dgt + 1))) == prefix);
            if (match) atomicAdd(&hist[(v >> (8 * dgt)) & 255u], 1u);
        }
        __syncthreads();
        if (tid == 0) {
            int acc = 0;
            int j = 255;
            for (; j >= 0; --j) {
                acc += (int)hist[j];
                if (acc >= k) break;
            }
            sh_k = k - (acc - (int)hist[j]);
            sh_prefix = (prefix << 8) | (unsigned)j;
        }
        __syncthreads();
        prefix = sh_prefix;
        k = sh_k;
        __syncthreads();
    }

    float thr = __uint_as_float(prefix);
    float sum = 0.f;
    int cnt = 0;
    for (int i = tid; i < M; i += 256) {
        float v = s[i];
        if (v > thr) { sum += v; cnt++; }
    }
#pragma unroll
    for (int off = 32; off > 0; off >>= 1) {
        sum += __shfl_xor(sum, off);
        cnt += __shfl_xor(cnt, off);
    }
    __shared__ float wsum[4];
    __shared__ int wcnt[4];
    int wv = tid >> 6;
    if ((tid & 63) == 0) { wsum[wv] = sum; wcnt[wv] = cnt; }
    __syncthreads();
    if (tid == 0) {
        float s2 = 0.f;
        int c2 = 0;
        for (int i = 0; i < 4; ++i) { s2 += wsum[i]; c2 += wcnt[i]; }
        score[b] = (s2 + (float)(TOPK - c2) * thr) * (1.0f / TOPK);
    }
}

extern "C" void kernel_launch(void* const* d_in, const int* in_sizes, int n_in,
                              void* d_out, int out_size, void* d_ws, size_t ws_size,
                              hipStream_t stream) {
    const float* mid = (const float*)d_in[0];
    const float* last = (const float*)d_in[1];
    const float* pmid = (const float*)d_in[2];
    const float* plast = (const float*)d_in[3];
    int B = in_sizes[0] / (NPATCH * C);  // 16

    float* out_map = (float*)d_out;                   // B*448*448
    float* out_score = out_map + (size_t)B * HW;      // B

    float* combined = (float*)d_ws;                   // B*1024 floats (64KB)
    int* meta = (int*)(combined + (size_t)B * NPATCH);
    int* ccount = meta;                               // B ints
    int* selbin = meta + B;                           // B ints
    float* bufA = (float*)((char*)d_ws + 68 * 1024);  // B*HW floats (12.8MB)
    unsigned* hist = (unsigned*)bufA;                 // B*8192 (overlays bufA)
    float* cand = bufA;                               // candidates (after hist consumed)

    int rows = B * NPATCH;
    anom_kernel<<<(rows + 3) / 4, 256, 0, stream>>>(mid, last, pmid, plast,
                                                    combined, rows);
    int total = B * HW;
    upsample_kernel<<<(total + 255) / 256, 256, 0, stream>>>(combined, out_map,
                                                             total);
    int nblk = B * 49;
    blur_kernel<2><<<nblk, 256, 0, stream>>>(out_map, bufA);
    blur_kernel<2><<<nblk, 256, 0, stream>>>(bufA, out_map);
    blur_kernel<2><<<nblk, 256, 0, stream>>>(out_map, bufA);
    blur_kernel<2><<<nblk, 256, 0, stream>>>(bufA, out_map);
    blur_kernel<2><<<nblk, 256, 0, stream>>>(out_map, bufA);
    blur_kernel<3><<<nblk, 256, 0, stream>>>(bufA, out_map);
    blur_kernel<3><<<nblk, 256, 0, stream>>>(out_map, bufA);
    blur_kernel<3><<<nblk, 256, 0, stream>>>(bufA, out_map);

    // exact top-k pipeline (scratch overlays bufA, which is free now)
    int nh = B * HBINS;
    zero_kernel<<<(nh + 255) / 256, 256, 0, stream>>>(hist, ccount, nh, B);
    hist_kernel<<<B * SLICES, 256, 0, stream>>>(out_map, hist);
    select_kernel<<<B, 256, 0, stream>>>(hist, selbin);
    compact_kernel<<<(total + 255) / 256, 256, 0, stream>>>(out_map, selbin,
                                                            ccount, cand);
    topk_kernel<<<B, 256, 0, stream>>>(cand, ccount, out_score);
}

// Round 3
// 224.017 us; speedup vs baseline: 3.4930x; 1.4994x over previous
//
#include <hip/hip_runtime.h>

constexpr int C = 768;
constexpr int NPATCH = 1024;   // (448/14)^2
constexpr int H = 448, W = 448;
constexpr int HW = H * W;      // 200704
constexpr int TOPK = 200;      // int(200704 * 0.001)
constexpr float EPS = 1e-12f;

constexpr int HBITS = 13;
constexpr int HBINS = 1 << HBITS;   // 8192
constexpr int HSHIFT = 18;          // bin = float_bits >> 18 (sign always 0)
constexpr int SLICES = 32;          // hist blocks per batch
constexpr int CSTRIDE = 64;         // ints between per-batch counters (256B)

__device__ __forceinline__ float dot4(const float4 a, const float4 b) {
    return a.x * b.x + a.y * b.y + a.z * b.z + a.w * b.w;
}

// One wave (64 lanes) per (b, n) row.
__global__ __launch_bounds__(256) void anom_kernel(
    const float* __restrict__ m, const float* __restrict__ l,
    const float* __restrict__ pm, const float* __restrict__ pl,
    float* __restrict__ combined, int rows) {
    int wid = (int)((blockIdx.x * blockDim.x + threadIdx.x) >> 6);
    int lane = threadIdx.x & 63;
    if (wid >= rows) return;
    size_t base = (size_t)wid * C;
    const float4* m4 = (const float4*)(m + base);
    const float4* l4 = (const float4*)(l + base);
    const float4* pm4 = (const float4*)(pm + base);
    const float4* pl4 = (const float4*)(pl + base);

    float4 vm[3], vl[3], vpm[3], vpl[3];
    float sm = 0.f, sl = 0.f, spm = 0.f, spl = 0.f;
#pragma unroll
    for (int j = 0; j < 3; ++j) {
        vm[j] = m4[lane + 64 * j];
        vl[j] = l4[lane + 64 * j];
        vpm[j] = pm4[lane + 64 * j];
        vpl[j] = pl4[lane + 64 * j];
        sm += dot4(vm[j], vm[j]);
        sl += dot4(vl[j], vl[j]);
        spm += dot4(vpm[j], vpm[j]);
        spl += dot4(vpl[j], vpl[j]);
    }
#pragma unroll
    for (int off = 32; off > 0; off >>= 1) {
        sm += __shfl_xor(sm, off);
        sl += __shfl_xor(sl, off);
        spm += __shfl_xor(spm, off);
        spl += __shfl_xor(spl, off);
    }
    float rm = 1.0f / fmaxf(sqrtf(sm), EPS);
    float rl = 1.0f / fmaxf(sqrtf(sl), EPS);
    float rpm = 1.0f / fmaxf(sqrtf(spm), EPS);
    float rpl = 1.0f / fmaxf(sqrtf(spl), EPS);

    float dm = 0.f, dl = 0.f;
#pragma unroll
    for (int j = 0; j < 3; ++j) {
        float d;
        d = vpm[j].x * rpm - vm[j].x * rm; dm += d * d;
        d = vpm[j].y * rpm - vm[j].y * rm; dm += d * d;
        d = vpm[j].z * rpm - vm[j].z * rm; dm += d * d;
        d = vpm[j].w * rpm - vm[j].w * rm; dm += d * d;
        d = vpl[j].x * rpl - vl[j].x * rl; dl += d * d;
        d = vpl[j].y * rpl - vl[j].y * rl; dl += d * d;
        d = vpl[j].z * rpl - vl[j].z * rl; dl += d * d;
        d = vpl[j].w * rpl - vl[j].w * rl; dl += d * d;
    }
#pragma unroll
    for (int off = 32; off > 0; off >>= 1) {
        dm += __shfl_xor(dm, off);
        dl += __shfl_xor(dl, off);
    }
    if (lane == 0) combined[wid] = sqrtf(dm) * sqrtf(dl);
}

__device__ __forceinline__ float bilerp32(const float* __restrict__ s,
                                          int gy, int gx) {
    float sx = (gx + 0.5f) * (1.0f / 14.0f) - 0.5f;
    float sy = (gy + 0.5f) * (1.0f / 14.0f) - 0.5f;
    float fx0 = floorf(sx), fy0 = floorf(sy);
    float fx = sx - fx0, fy = sy - fy0;
    int x0 = (int)fx0, y0 = (int)fy0;
    int x0c = min(max(x0, 0), 31);
    int x1c = min(max(x0 + 1, 0), 31);
    int y0c = min(max(y0, 0), 31);
    int y1c = min(max(y0 + 1, 0), 31);
    float v00 = s[y0c * 32 + x0c], v01 = s[y0c * 32 + x1c];
    float v10 = s[y1c * 32 + x0c], v11 = s[y1c * 32 + x1c];
    return (1.f - fy) * ((1.f - fx) * v00 + fx * v01) +
           fy * ((1.f - fx) * v10 + fx * v11);
}

// Fused NP passes of (2P+1)x(2P+1) zero-padded box blur on a 64x64 output
// tile with halo HALO = NP*P. UPS: input is bilinear-upsampled 32x32 source.
// Invariant between passes: buf holds pass-input with 0 at out-of-image cells.
template <int P, int NP, bool UPS>
__global__ __launch_bounds__(256) void blur_fused_kernel(
    const float* __restrict__ src, float* __restrict__ dst) {
    constexpr int T = 64;
    constexpr int HALO = NP * P;
    constexpr int BS = T + 2 * HALO;
    constexpr int BW = BS + 1;          // LDS row stride (pad)
    constexpr float inv = 1.0f / (2 * P + 1);
    __shared__ float buf[BS * BW];
    __shared__ float tmp[BS * BW];

    int tilex = blockIdx.x % 7;
    int tiley = (blockIdx.x / 7) % 7;
    int b = blockIdx.x / 49;
    int ox0 = tilex * T, oy0 = tiley * T;
    int tid = threadIdx.x;

    if (UPS) {
        const float* s = src + (size_t)b * NPATCH;
        for (int i = tid; i < BS * BS; i += 256) {
            int r = i / BS, c = i % BS;
            int gy = oy0 + r - HALO, gx = ox0 + c - HALO;
            float v = 0.f;
            if (gy >= 0 && gy < H && gx >= 0 && gx < W) v = bilerp32(s, gy, gx);
            buf[r * BW + c] = v;
        }
    } else {
        const float* s = src + (size_t)b * HW;
        for (int i = tid; i < BS * BS; i += 256) {
            int r = i / BS, c = i % BS;
            int gy = oy0 + r - HALO, gx = ox0 + c - HALO;
            float v = 0.f;
            if (gy >= 0 && gy < H && gx >= 0 && gx < W) v = s[gy * W + gx];
            buf[r * BW + c] = v;
        }
    }
    __syncthreads();

    constexpr int CW = BS - 2 * P;  // computed width per pass
#pragma unroll 1
    for (int pass = 0; pass < NP; ++pass) {
        // H: tmp[r][c] for all rows, c in [P, BS-P)
        for (int i = tid; i < BS * CW; i += 256) {
            int r = i / CW, c = P + i % CW;
            const float* p = &buf[r * BW + c - P];
            float a = 0.f;
#pragma unroll
            for (int j = 0; j <= 2 * P; ++j) a += p[j];
            tmp[r * BW + c] = a * inv;
        }
        __syncthreads();
        // V + out-of-image re-zero: buf[r][c] for r,c in [P, BS-P)
        for (int i = tid; i < CW * CW; i += 256) {
            int r = P + i / CW, c = P + i % CW;
            const float* p = &tmp[(r - P) * BW + c];
            float a = 0.f;
#pragma unroll
            for (int j = 0; j <= 2 * P; ++j) a += p[j * BW];
            int gy = oy0 + r - HALO, gx = ox0 + c - HALO;
            bool in_img = (gy >= 0 && gy < H && gx >= 0 && gx < W);
            buf[r * BW + c] = in_img ? a * inv : 0.f;
        }
        __syncthreads();
    }

    float* d = dst + (size_t)b * HW;
    for (int i = tid; i < T * T; i += 256) {
        int r = i / T, c = i % T;
        d[(size_t)(oy0 + r) * W + (ox0 + c)] =
            buf[(HALO + r) * BW + (HALO + c)];
    }
}

// ---------------- grid-parallel exact top-k ----------------

__global__ __launch_bounds__(256) void zero_kernel(unsigned* __restrict__ hist,
                                                   int* __restrict__ meta,
                                                   int nh, int nmeta) {
    int i = blockIdx.x * blockDim.x + threadIdx.x;
    if (i < nh) hist[i] = 0;
    if (i < nmeta) meta[i] = 0;
}

// Per-batch 8192-bin histogram of top-13 float bits.
__global__ __launch_bounds__(256) void hist_kernel(
    const float* __restrict__ map, unsigned* __restrict__ hist) {
    __shared__ unsigned lh[HBINS];
    int b = blockIdx.x / SLICES, sl = blockIdx.x % SLICES;
    for (int i = threadIdx.x; i < HBINS; i += 256) lh[i] = 0;
    __syncthreads();
    const unsigned* u = (const unsigned*)(map + (size_t)b * HW);
    int per = HW / SLICES;  // 6272
    int start = sl * per;
    for (int i = start + threadIdx.x; i < start + per; i += 256)
        atomicAdd(&lh[u[i] >> HSHIFT], 1u);
    __syncthreads();
    unsigned* gh = hist + (size_t)b * HBINS;
    for (int i = threadIdx.x; i < HBINS; i += 256) {
        unsigned c = lh[i];
        if (c) atomicAdd(&gh[i], c);
    }
}

// Per batch: largest bin with count(bins >= selbin) >= TOPK.
__global__ __launch_bounds__(256) void select_kernel(
    const unsigned* __restrict__ hist, int* __restrict__ selbin) {
    int b = blockIdx.x;
    const unsigned* gh = hist + (size_t)b * HBINS;
    constexpr int CHUNK = HBINS / 256;  // 32
    __shared__ unsigned csum[256];
    int tid = threadIdx.x;
    unsigned s = 0;
#pragma unroll
    for (int j = 0; j < CHUNK; ++j) s += gh[tid * CHUNK + j];
    csum[tid] = s;
    __syncthreads();
    if (tid == 0) {
        unsigned acc = 0;
        int t = 255;
        for (; t > 0; --t) {
            if (acc + csum[t] >= TOPK) break;
            acc += csum[t];
        }
        int base = t * CHUNK;
        int j = CHUNK - 1;
        for (; j > 0; --j) {
            unsigned c = gh[base + j];
            if (acc + c >= TOPK) break;
            acc += c;
        }
        selbin[b * CSTRIDE] = base + j;
    }
}

// Append values with bin >= selbin[b] to cand[b*HW ...].
// Each block covers 1024 consecutive elems (single batch). One global atomic
// per block; per-thread offsets via LDS atomic (rare takers only).
__global__ __launch_bounds__(256) void compact_kernel(
    const float* __restrict__ map, const int* __restrict__ selbin,
    int* __restrict__ ccount, float* __restrict__ cand) {
    int tid = threadIdx.x;
    size_t base = (size_t)blockIdx.x * 1024;
    int b = (int)(base / HW);
    int sb = selbin[b * CSTRIDE];
    const uint4* u4 = (const uint4*)(((const unsigned*)map) + base);
    uint4 v = u4[tid];
    unsigned take0 = ((int)(v.x >> HSHIFT) >= sb);
    unsigned take1 = ((int)(v.y >> HSHIFT) >= sb);
    unsigned take2 = ((int)(v.z >> HSHIFT) >= sb);
    unsigned take3 = ((int)(v.w >> HSHIFT) >= sb);
    int c = (int)(take0 + take1 + take2 + take3);

    __shared__ int blkcnt, blkbase;
    if (tid == 0) blkcnt = 0;
    __syncthreads();
    int pos = 0;
    if (c) pos = atomicAdd(&blkcnt, c);
    __syncthreads();
    if (tid == 0 && blkcnt > 0)
        blkbase = atomicAdd(&ccount[b * CSTRIDE], blkcnt);
    __syncthreads();
    if (c) {
        float* o = cand + (size_t)b * HW + blkbase + pos;
        if (take0) *o++ = __uint_as_float(v.x);
        if (take1) *o++ = __uint_as_float(v.y);
        if (take2) *o++ = __uint_as_float(v.z);
        if (take3) *o = __uint_as_float(v.w);
    }
}

// Exact top-200 mean per batch via radix select over the candidate set.
__global__ __launch_bounds__(256) void topk_kernel(
    const float* __restrict__ cand, const int* __restrict__ ccount,
    float* __restrict__ score) {
    int b = blockIdx.x;
    const float* s = cand + (size_t)b * HW;
    const unsigned* u = (const unsigned*)s;
    int M = ccount[b * CSTRIDE];
    __shared__ unsigned hist[256];
    __shared__ unsigned sh_prefix;
    __shared__ int sh_k;
    int tid = threadIdx.x;

    unsigned prefix = 0;
    int k = TOPK;
    for (int dgt = 3; dgt >= 0; --dgt) {
        hist[tid] = 0;
        __syncthreads();
        for (int i = tid; i < M; i += 256) {
            unsigned v = u[i];
            bool match;
            if (dgt == 3) match = true;
            else match = ((v >> (8 * (dgt + 1))) == prefix);
            if (match) atomicAdd(&hist[(v >> (8 * dgt)) & 255u], 1u);
        }
        __syncthreads();
        if (tid == 0) {
            int acc = 0;
            int j = 255;
            for (; j >= 0; --j) {
                acc += (int)hist[j];
                if (acc >= k) break;
            }
            sh_k = k - (acc - (int)hist[j]);
            sh_prefix = (prefix << 8) | (unsigned)j;
        }
        __syncthreads();
        prefix = sh_prefix;
        k = sh_k;
        __syncthreads();
    }

    float thr = __uint_as_float(prefix);
    float sum = 0.f;
    int cnt = 0;
    for (int i = tid; i < M; i += 256) {
        float v = s[i];
        if (v > thr) { sum += v; cnt++; }
    }
#pragma unroll
    for (int off = 32; off > 0; off >>= 1) {
        sum += __shfl_xor(sum, off);
        cnt += __shfl_xor(cnt, off);
    }
    __shared__ float wsum[4];
    __shared__ int wcnt[4];
    int wv = tid >> 6;
    if ((tid & 63) == 0) { wsum[wv] = sum; wcnt[wv] = cnt; }
    __syncthreads();
    if (tid == 0) {
        float s2 = 0.f;
        int c2 = 0;
        for (int i = 0; i < 4; ++i) { s2 += wsum[i]; c2 += wcnt[i]; }
        score[b] = (s2 + (float)(TOPK - c2) * thr) * (1.0f / TOPK);
    }
}

extern "C" void kernel_launch(void* const* d_in, const int* in_sizes, int n_in,
                              void* d_out, int out_size, void* d_ws, size_t ws_size,
                              hipStream_t stream) {
    const float* mid = (const float*)d_in[0];
    const float* last = (const float*)d_in[1];
    const float* pmid = (const float*)d_in[2];
    const float* plast = (const float*)d_in[3];
    int B = in_sizes[0] / (NPATCH * C);  // 16

    float* out_map = (float*)d_out;                   // B*448*448
    float* out_score = out_map + (size_t)B * HW;      // B

    // ws layout: combined (64KB) | meta: ccount,selbin strided (8KB) | bufA
    float* combined = (float*)d_ws;
    int* meta = (int*)((char*)d_ws + 64 * 1024);
    int* ccount = meta;                               // [b*CSTRIDE]
    int* selbin = meta + 16 * CSTRIDE;                // [b*CSTRIDE], own lines
    float* bufA = (float*)((char*)d_ws + 72 * 1024);  // B*HW floats
    unsigned* hist = (unsigned*)bufA;                 // overlays bufA
    float* cand = bufA;                               // overlays bufA

    int rows = B * NPATCH;
    anom_kernel<<<(rows + 3) / 4, 256, 0, stream>>>(mid, last, pmid, plast,
                                                    combined, rows);
    int nblk = B * 49;
    // 5 fused passes of 5x5 (input: bilinear-upsampled combined) -> bufA
    blur_fused_kernel<2, 5, true><<<nblk, 256, 0, stream>>>(combined, bufA);
    // 3 fused passes of 7x7 -> out_map
    blur_fused_kernel<3, 3, false><<<nblk, 256, 0, stream>>>(bufA, out_map);

    // exact top-k pipeline (hist/cand overlay bufA, free now)
    int nh = B * HBINS;
    int nmeta = 2 * 16 * CSTRIDE;
    zero_kernel<<<(nh + 255) / 256, 256, 0, stream>>>(hist, meta, nh, nmeta);
    hist_kernel<<<B * SLICES, 256, 0, stream>>>(out_map, hist);
    select_kernel<<<B, 256, 0, stream>>>(hist, selbin);
    int nc = (B * HW) / 1024;
    compact_kernel<<<nc, 256, 0, stream>>>(out_map, selbin, ccount, cand);
    topk_kernel<<<B, 256, 0, stream>>>(cand, ccount, out_score);
}

// Round 4
// 166.611 us; speedup vs baseline: 4.6965x; 1.3446x over previous
//
#include <hip/hip_runtime.h>

constexpr int C = 768;
constexpr int NPATCH = 1024;   // (448/14)^2
constexpr int H = 448, W = 448;
constexpr int HW = H * W;      // 200704
constexpr int TOPK = 200;      // int(200704 * 0.001)
constexpr float EPS = 1e-12f;

constexpr int HBITS = 13;
constexpr int HBINS = 1 << HBITS;   // 8192
constexpr int HSHIFT = 18;          // bin = float_bits >> 18 (sign always 0)
constexpr int SLICES = 32;          // hist blocks per batch
constexpr int CSTRIDE = 64;         // ints between per-batch counters (256B)

__device__ __forceinline__ float dot4(const float4 a, const float4 b) {
    return a.x * b.x + a.y * b.y + a.z * b.z + a.w * b.w;
}

// One wave per (b,n) row. Uses ||a/Ma - b/Mb||^2 = aa/Ma^2 - 2ab/(Ma*Mb) + bb/Mb^2
// (Ma = max(||a||, eps)) so no values must stay live across the reduction.
__global__ __launch_bounds__(256, 4) void anom_kernel(
    const float* __restrict__ m, const float* __restrict__ l,
    const float* __restrict__ pm, const float* __restrict__ pl,
    float* __restrict__ combined, int rows) {
    int wid = (int)((blockIdx.x * blockDim.x + threadIdx.x) >> 6);
    int lane = threadIdx.x & 63;
    if (wid >= rows) return;
    size_t base = (size_t)wid * C;
    const float4* A = (const float4*)(m + base);
    const float4* B = (const float4*)(pm + base);
    const float4* Cc = (const float4*)(l + base);
    const float4* D = (const float4*)(pl + base);

    float4 a0 = A[lane], a1 = A[lane + 64], a2 = A[lane + 128];
    float4 b0 = B[lane], b1 = B[lane + 64], b2 = B[lane + 128];
    float4 c0 = Cc[lane], c1 = Cc[lane + 64], c2 = Cc[lane + 128];
    float4 d0 = D[lane], d1 = D[lane + 64], d2 = D[lane + 128];

    float mm = dot4(a0, a0) + dot4(a1, a1) + dot4(a2, a2);
    float pp = dot4(b0, b0) + dot4(b1, b1) + dot4(b2, b2);
    float mp = dot4(a0, b0) + dot4(a1, b1) + dot4(a2, b2);
    float ll = dot4(c0, c0) + dot4(c1, c1) + dot4(c2, c2);
    float qq = dot4(d0, d0) + dot4(d1, d1) + dot4(d2, d2);
    float lq = dot4(c0, d0) + dot4(c1, d1) + dot4(c2, d2);

#pragma unroll
    for (int off = 32; off > 0; off >>= 1) {
        mm += __shfl_xor(mm, off);
        pp += __shfl_xor(pp, off);
        mp += __shfl_xor(mp, off);
        ll += __shfl_xor(ll, off);
        qq += __shfl_xor(qq, off);
        lq += __shfl_xor(lq, off);
    }
    if (lane == 0) {
        float rm = 1.0f / fmaxf(sqrtf(mm), EPS);
        float rp = 1.0f / fmaxf(sqrtf(pp), EPS);
        float rl = 1.0f / fmaxf(sqrtf(ll), EPS);
        float rq = 1.0f / fmaxf(sqrtf(qq), EPS);
        float d2m = fmaxf(mm * rm * rm - 2.f * mp * rm * rp + pp * rp * rp, 0.f);
        float d2l = fmaxf(ll * rl * rl - 2.f * lq * rl * rq + qq * rq * rq, 0.f);
        combined[wid] = sqrtf(d2m) * sqrtf(d2l);
    }
}

__device__ __forceinline__ float bilerp32(const float* __restrict__ s,
                                          int gy, int gx) {
    float sx = (gx + 0.5f) * (1.0f / 14.0f) - 0.5f;
    float sy = (gy + 0.5f) * (1.0f / 14.0f) - 0.5f;
    float fx0 = floorf(sx), fy0 = floorf(sy);
    float fx = sx - fx0, fy = sy - fy0;
    int x0 = (int)fx0, y0 = (int)fy0;
    int x0c = min(max(x0, 0), 31);
    int x1c = min(max(x0 + 1, 0), 31);
    int y0c = min(max(y0, 0), 31);
    int y1c = min(max(y0 + 1, 0), 31);
    float v00 = s[y0c * 32 + x0c], v01 = s[y0c * 32 + x1c];
    float v10 = s[y1c * 32 + x0c], v11 = s[y1c * 32 + x1c];
    return (1.f - fy) * ((1.f - fx) * v00 + fx * v01) +
           fy * ((1.f - fx) * v10 + fx * v11);
}

// Fused NP passes of (2P+1)^2 zero-padded box blur, 64x64 output tile,
// sliding-origin LDS scheme: before pass p, buf[r][c] = I_p(oy0-HALO+p*P+r,
// ox0-HALO+p*P+c), valid extent S=BS-2pP. All LDS access is b128.
// Over-reads past valid extent never feed taps of valid outputs.
template <int P, int NP, bool UPS>
__global__ __launch_bounds__(512) void blur_fused_kernel(
    const float* __restrict__ src, float* __restrict__ dst) {
    constexpr int T = 64;
    constexpr int HALO = NP * P;
    constexpr int BS = T + 2 * HALO;   // 84 (P2) / 82 (P3)
    constexpr int BW = 84;             // row stride (words), mult of 4
    constexpr float inv = 1.0f / (2 * P + 1);
    __shared__ float buf[BS * BW];
    __shared__ float tmp[84 * BW];

    int tilex = blockIdx.x % 7;
    int tiley = (blockIdx.x / 7) % 7;
    int b = blockIdx.x / 49;
    int ox0 = tilex * T, oy0 = tiley * T;
    int tid = threadIdx.x;

    if (UPS) {
        const float* s = src + (size_t)b * NPATCH;
        for (int i = tid; i < NPATCH; i += 512) tmp[i] = s[i];
        __syncthreads();
        for (int i = tid; i < BS * BS; i += 512) {
            int r = i / BS, c = i % BS;
            int gy = oy0 + r - HALO, gx = ox0 + c - HALO;
            float v = 0.f;
            if (gy >= 0 && gy < H && gx >= 0 && gx < W) v = bilerp32(tmp, gy, gx);
            buf[r * BW + c] = v;
        }
    } else {
        const float* s = src + (size_t)b * HW;
        for (int i = tid; i < BS * BS; i += 512) {
            int r = i / BS, c = i % BS;
            int gy = oy0 + r - HALO, gx = ox0 + c - HALO;
            float v = 0.f;
            if (gy >= 0 && gy < H && gx >= 0 && gx < W) v = s[gy * W + gx];
            buf[r * BW + c] = v;
        }
    }
    __syncthreads();

#pragma unroll 1
    for (int pass = 0; pass < NP; ++pass) {
        int S = BS - 2 * pass * P;
        int wOut = S - 2 * P;
        int ncell = (wOut + 3) >> 2;
        // H: tmp[r][cc..cc+3] = avg_{j<=2P} buf[r][cc+j]
        int cellsH = S * ncell;
        for (int i = tid; i < cellsH; i += 512) {
            int r = i / ncell, cc = (i % ncell) * 4;
            const float* bp = &buf[r * BW + cc];
            float4 A = *(const float4*)bp;
            float4 Bv = *(const float4*)(bp + 4);
            float o0, o1, o2, o3;
            if (P == 2) {
                float t = A.x + A.y + A.z + A.w + Bv.x;
                o0 = t;
                t += Bv.y - A.x; o1 = t;
                t += Bv.z - A.y; o2 = t;
                t += Bv.w - A.z; o3 = t;
            } else {
                float4 Cv = *(const float4*)(bp + 8);
                float t = A.x + A.y + A.z + A.w + Bv.x + Bv.y + Bv.z;
                o0 = t;
                t += Bv.w - A.x; o1 = t;
                t += Cv.x - A.y; o2 = t;
                t += Cv.y - A.z; o3 = t;
            }
            *(float4*)&tmp[r * BW + cc] =
                make_float4(o0 * inv, o1 * inv, o2 * inv, o3 * inv);
        }
        __syncthreads();
        // V + out-of-image re-zero: buf[r][cc..cc+3] = avg_{j<=2P} tmp[r+j][cc..]
        int org = (pass + 1) * P;
        int cellsV = wOut * ncell;
        for (int i = tid; i < cellsV; i += 512) {
            int r = i / ncell, cc = (i % ncell) * 4;
            float4 acc = *(const float4*)&tmp[r * BW + cc];
#pragma unroll
            for (int j = 1; j <= 2 * P; ++j) {
                float4 v = *(const float4*)&tmp[(r + j) * BW + cc];
                acc.x += v.x; acc.y += v.y; acc.z += v.z; acc.w += v.w;
            }
            int gy = oy0 - HALO + org + r;
            int gx = ox0 - HALO + org + cc;
            bool ry = (gy >= 0 && gy < H);
            float4 o;
            o.x = (ry && gx >= 0 && gx < W) ? acc.x * inv : 0.f;
            o.y = (ry && gx + 1 >= 0 && gx + 1 < W) ? acc.y * inv : 0.f;
            o.z = (ry && gx + 2 >= 0 && gx + 2 < W) ? acc.z * inv : 0.f;
            o.w = (ry && gx + 3 >= 0 && gx + 3 < W) ? acc.w * inv : 0.f;
            *(float4*)&buf[r * BW + cc] = o;
        }
        __syncthreads();
    }

    // After NP passes buf[r][c] = I_NP(oy0+r, ox0+c), r,c in [0,T)
    float* d = dst + (size_t)b * HW;
    for (int i = tid; i < T * (T / 4); i += 512) {
        int r = i / (T / 4), cc = (i % (T / 4)) * 4;
        *(float4*)&d[(size_t)(oy0 + r) * W + ox0 + cc] =
            *(const float4*)&buf[r * BW + cc];
    }
}

// ---------------- grid-parallel exact top-k ----------------

__global__ __launch_bounds__(256) void zero_kernel(unsigned* __restrict__ hist,
                                                   int* __restrict__ meta,
                                                   int nh, int nmeta) {
    int i = blockIdx.x * blockDim.x + threadIdx.x;
    if (i < nh) hist[i] = 0;
    if (i < nmeta) meta[i] = 0;
}

__global__ __launch_bounds__(256) void hist_kernel(
    const float* __restrict__ map, unsigned* __restrict__ hist) {
    __shared__ unsigned lh[HBINS];
    int b = blockIdx.x / SLICES, sl = blockIdx.x % SLICES;
    for (int i = threadIdx.x; i < HBINS; i += 256) lh[i] = 0;
    __syncthreads();
    const unsigned* u = (const unsigned*)(map + (size_t)b * HW);
    int per = HW / SLICES;  // 6272
    int start = sl * per;
    for (int i = start + threadIdx.x; i < start + per; i += 256)
        atomicAdd(&lh[u[i] >> HSHIFT], 1u);
    __syncthreads();
    unsigned* gh = hist + (size_t)b * HBINS;
    for (int i = threadIdx.x; i < HBINS; i += 256) {
        unsigned c = lh[i];
        if (c) atomicAdd(&gh[i], c);
    }
}

__global__ __launch_bounds__(256) void select_kernel(
    const unsigned* __restrict__ hist, int* __restrict__ selbin) {
    int b = blockIdx.x;
    const unsigned* gh = hist + (size_t)b * HBINS;
    constexpr int CHUNK = HBINS / 256;  // 32
    __shared__ unsigned csum[256];
    int tid = threadIdx.x;
    unsigned s = 0;
#pragma unroll
    for (int j = 0; j < CHUNK; ++j) s += gh[tid * CHUNK + j];
    csum[tid] = s;
    __syncthreads();
    if (tid == 0) {
        unsigned acc = 0;
        int t = 255;
        for (; t > 0; --t) {
            if (acc + csum[t] >= TOPK) break;
            acc += csum[t];
        }
        int base = t * CHUNK;
        int j = CHUNK - 1;
        for (; j > 0; --j) {
            unsigned c = gh[base + j];
            if (acc + c >= TOPK) break;
            acc += c;
        }
        selbin[b * CSTRIDE] = base + j;
    }
}

__global__ __launch_bounds__(256) void compact_kernel(
    const float* __restrict__ map, const int* __restrict__ selbin,
    int* __restrict__ ccount, float* __restrict__ cand) {
    int tid = threadIdx.x;
    size_t base = (size_t)blockIdx.x * 1024;
    int b = (int)(base / HW);
    int sb = selbin[b * CSTRIDE];
    const uint4* u4 = (const uint4*)(((const unsigned*)map) + base);
    uint4 v = u4[tid];
    unsigned take0 = ((int)(v.x >> HSHIFT) >= sb);
    unsigned take1 = ((int)(v.y >> HSHIFT) >= sb);
    unsigned take2 = ((int)(v.z >> HSHIFT) >= sb);
    unsigned take3 = ((int)(v.w >> HSHIFT) >= sb);
    int c = (int)(take0 + take1 + take2 + take3);

    __shared__ int blkcnt, blkbase;
    if (tid == 0) blkcnt = 0;
    __syncthreads();
    int pos = 0;
    if (c) pos = atomicAdd(&blkcnt, c);
    __syncthreads();
    if (tid == 0 && blkcnt > 0)
        blkbase = atomicAdd(&ccount[b * CSTRIDE], blkcnt);
    __syncthreads();
    if (c) {
        float* o = cand + (size_t)b * HW + blkbase + pos;
        if (take0) *o++ = __uint_as_float(v.x);
        if (take1) *o++ = __uint_as_float(v.y);
        if (take2) *o++ = __uint_as_float(v.z);
        if (take3) *o = __uint_as_float(v.w);
    }
}

__global__ __launch_bounds__(256) void topk_kernel(
    const float* __restrict__ cand, const int* __restrict__ ccount,
    float* __restrict__ score) {
    int b = blockIdx.x;
    const float* s = cand + (size_t)b * HW;
    const unsigned* u = (const unsigned*)s;
    int M = ccount[b * CSTRIDE];
    __shared__ unsigned hist[256];
    __shared__ unsigned sh_prefix;
    __shared__ int sh_k;
    int tid = threadIdx.x;

    unsigned prefix = 0;
    int k = TOPK;
    for (int dgt = 3; dgt >= 0; --dgt) {
        hist[tid] = 0;
        __syncthreads();
        for (int i = tid; i < M; i += 256) {
            unsigned v = u[i];
            bool match;
            if (dgt == 3) match = true;
            else match = ((v >> (8 * (dgt + 1))) == prefix);
            if (match) atomicAdd(&hist[(v >> (8 * dgt)) & 255u], 1u);
        }
        __syncthreads();
        if (tid == 0) {
            int acc = 0;
            int j = 255;
            for (; j >= 0; --j) {
                acc += (int)hist[j];
                if (acc >= k) break;
            }
            sh_k = k - (acc - (int)hist[j]);
            sh_prefix = (prefix << 8) | (unsigned)j;
        }
        __syncthreads();
        prefix = sh_prefix;
        k = sh_k;
        __syncthreads();
    }

    float thr = __uint_as_float(prefix);
    float sum = 0.f;
    int cnt = 0;
    for (int i = tid; i < M; i += 256) {
        float v = s[i];
        if (v > thr) { sum += v; cnt++; }
    }
#pragma unroll
    for (int off = 32; off > 0; off >>= 1) {
        sum += __shfl_xor(sum, off);
        cnt += __shfl_xor(cnt, off);
    }
    __shared__ float wsum[4];
    __shared__ int wcnt[4];
    int wv = tid >> 6;
    if ((tid & 63) == 0) { wsum[wv] = sum; wcnt[wv] = cnt; }
    __syncthreads();
    if (tid == 0) {
        float s2 = 0.f;
        int c2 = 0;
        for (int i = 0; i < 4; ++i) { s2 += wsum[i]; c2 += wcnt[i]; }
        score[b] = (s2 + (float)(TOPK - c2) * thr) * (1.0f / TOPK);
    }
}

extern "C" void kernel_launch(void* const* d_in, const int* in_sizes, int n_in,
                              void* d_out, int out_size, void* d_ws, size_t ws_size,
                              hipStream_t stream) {
    const float* mid = (const float*)d_in[0];
    const float* last = (const float*)d_in[1];
    const float* pmid = (const float*)d_in[2];
    const float* plast = (const float*)d_in[3];
    int B = in_sizes[0] / (NPATCH * C);  // 16

    float* out_map = (float*)d_out;                   // B*448*448
    float* out_score = out_map + (size_t)B * HW;      // B

    float* combined = (float*)d_ws;
    int* meta = (int*)((char*)d_ws + 64 * 1024);
    int* ccount = meta;                               // [b*CSTRIDE]
    int* selbin = meta + 16 * CSTRIDE;                // [b*CSTRIDE]
    float* bufA = (float*)((char*)d_ws + 72 * 1024);  // B*HW floats
    unsigned* hist = (unsigned*)bufA;                 // overlays bufA
    float* cand = bufA;                               // overlays bufA

    int rows = B * NPATCH;
    anom_kernel<<<(rows + 3) / 4, 256, 0, stream>>>(mid, last, pmid, plast,
                                                    combined, rows);
    int nblk = B * 49;
    blur_fused_kernel<2, 5, true><<<nblk, 512, 0, stream>>>(combined, bufA);
    blur_fused_kernel<3, 3, false><<<nblk, 512, 0, stream>>>(bufA, out_map);

    int nh = B * HBINS;
    int nmeta = 2 * 16 * CSTRIDE;
    zero_kernel<<<(nh + 255) / 256, 256, 0, stream>>>(hist, meta, nh, nmeta);
    hist_kernel<<<B * SLICES, 256, 0, stream>>>(out_map, hist);
    select_kernel<<<B, 256, 0, stream>>>(hist, selbin);
    int nc = (B * HW) / 1024;
    compact_kernel<<<nc, 256, 0, stream>>>(out_map, selbin, ccount, cand);
    topk_kernel<<<B, 256, 0, stream>>>(cand, ccount, out_score);
}

// Round 5
// 166.583 us; speedup vs baseline: 4.6973x; 1.0002x over previous
//
#include <hip/hip_runtime.h>

constexpr int C = 768;
constexpr int NPATCH = 1024;   // (448/14)^2
constexpr int H = 448, W = 448;
constexpr int HW = H * W;      // 200704
constexpr int TOPK = 200;      // int(200704 * 0.001)
constexpr float EPS = 1e-12f;

constexpr int HBITS = 13;
constexpr int HBINS = 1 << HBITS;   // 8192
constexpr int HSHIFT = 18;          // bin = float_bits >> 18 (sign always 0)
constexpr int SLICES = 32;          // hist blocks per batch
constexpr int CSTRIDE = 64;         // ints between per-batch counters (256B)

typedef float f32x4 __attribute__((ext_vector_type(4)));

__device__ __forceinline__ float dotv(const f32x4 a, const f32x4 b) {
    return a.x * b.x + a.y * b.y + a.z * b.z + a.w * b.w;
}

// One wave per (b,n) row. ||a/Ma - b/Mb||^2 = aa/Ma^2 - 2ab/(Ma*Mb) + bb/Mb^2.
// The asm keep-alive forces all 12 loads in flight simultaneously (the
// compiler otherwise minimizes VGPRs to 32 and serializes loads -> MLP-bound).
__global__ __launch_bounds__(256, 4) void anom_kernel(
    const float* __restrict__ m, const float* __restrict__ l,
    const float* __restrict__ pm, const float* __restrict__ pl,
    float* __restrict__ combined, int rows) {
    int wid = (int)((blockIdx.x * blockDim.x + threadIdx.x) >> 6);
    int lane = threadIdx.x & 63;
    if (wid >= rows) return;
    size_t base = (size_t)wid * C;
    const f32x4* A = (const f32x4*)(m + base);
    const f32x4* B = (const f32x4*)(pm + base);
    const f32x4* Cc = (const f32x4*)(l + base);
    const f32x4* D = (const f32x4*)(pl + base);

    f32x4 a0 = A[lane], a1 = A[lane + 64], a2 = A[lane + 128];
    f32x4 b0 = B[lane], b1 = B[lane + 64], b2 = B[lane + 128];
    f32x4 c0 = Cc[lane], c1 = Cc[lane + 64], c2 = Cc[lane + 128];
    f32x4 d0 = D[lane], d1 = D[lane + 64], d2 = D[lane + 128];
    asm volatile("" : "+v"(a0), "+v"(a1), "+v"(a2), "+v"(b0), "+v"(b1),
                      "+v"(b2), "+v"(c0), "+v"(c1), "+v"(c2), "+v"(d0),
                      "+v"(d1), "+v"(d2));

    float mm = dotv(a0, a0) + dotv(a1, a1) + dotv(a2, a2);
    float pp = dotv(b0, b0) + dotv(b1, b1) + dotv(b2, b2);
    float mp = dotv(a0, b0) + dotv(a1, b1) + dotv(a2, b2);
    float ll = dotv(c0, c0) + dotv(c1, c1) + dotv(c2, c2);
    float qq = dotv(d0, d0) + dotv(d1, d1) + dotv(d2, d2);
    float lq = dotv(c0, d0) + dotv(c1, d1) + dotv(c2, d2);

#pragma unroll
    for (int off = 32; off > 0; off >>= 1) {
        mm += __shfl_xor(mm, off);
        pp += __shfl_xor(pp, off);
        mp += __shfl_xor(mp, off);
        ll += __shfl_xor(ll, off);
        qq += __shfl_xor(qq, off);
        lq += __shfl_xor(lq, off);
    }
    if (lane == 0) {
        float rm = 1.0f / fmaxf(sqrtf(mm), EPS);
        float rp = 1.0f / fmaxf(sqrtf(pp), EPS);
        float rl = 1.0f / fmaxf(sqrtf(ll), EPS);
        float rq = 1.0f / fmaxf(sqrtf(qq), EPS);
        float d2m = fmaxf(mm * rm * rm - 2.f * mp * rm * rp + pp * rp * rp, 0.f);
        float d2l = fmaxf(ll * rl * rl - 2.f * lq * rl * rq + qq * rq * rq, 0.f);
        combined[wid] = sqrtf(d2m) * sqrtf(d2l);
    }
}

__device__ __forceinline__ float bilerp32(const float* __restrict__ s,
                                          int gy, int gx) {
    float sx = (gx + 0.5f) * (1.0f / 14.0f) - 0.5f;
    float sy = (gy + 0.5f) * (1.0f / 14.0f) - 0.5f;
    float fx0 = floorf(sx), fy0 = floorf(sy);
    float fx = sx - fx0, fy = sy - fy0;
    int x0 = (int)fx0, y0 = (int)fy0;
    int x0c = min(max(x0, 0), 31);
    int x1c = min(max(x0 + 1, 0), 31);
    int y0c = min(max(y0, 0), 31);
    int y1c = min(max(y0 + 1, 0), 31);
    float v00 = s[y0c * 32 + x0c], v01 = s[y0c * 32 + x1c];
    float v10 = s[y1c * 32 + x0c], v11 = s[y1c * 32 + x1c];
    return (1.f - fy) * ((1.f - fx) * v00 + fx * v01) +
           fy * ((1.f - fx) * v10 + fx * v11);
}

// Fused NP passes of (2P+1)^2 zero-padded box blur, 64x64 output tile,
// sliding-origin LDS scheme; all LDS access is b128.
template <int P, int NP, bool UPS>
__global__ __launch_bounds__(512) void blur_fused_kernel(
    const float* __restrict__ src, float* __restrict__ dst) {
    constexpr int T = 64;
    constexpr int HALO = NP * P;
    constexpr int BS = T + 2 * HALO;   // 84 (P2) / 82 (P3)
    constexpr int BW = 84;             // row stride (words), mult of 4
    constexpr float inv = 1.0f / (2 * P + 1);
    __shared__ float buf[BS * BW];
    __shared__ float tmp[84 * BW];

    int tilex = blockIdx.x % 7;
    int tiley = (blockIdx.x / 7) % 7;
    int b = blockIdx.x / 49;
    int ox0 = tilex * T, oy0 = tiley * T;
    int tid = threadIdx.x;

    if (UPS) {
        const float* s = src + (size_t)b * NPATCH;
        for (int i = tid; i < NPATCH; i += 512) tmp[i] = s[i];
        __syncthreads();
        for (int i = tid; i < BS * BS; i += 512) {
            int r = i / BS, c = i % BS;
            int gy = oy0 + r - HALO, gx = ox0 + c - HALO;
            float v = 0.f;
            if (gy >= 0 && gy < H && gx >= 0 && gx < W) v = bilerp32(tmp, gy, gx);
            buf[r * BW + c] = v;
        }
    } else {
        const float* s = src + (size_t)b * HW;
        for (int i = tid; i < BS * BS; i += 512) {
            int r = i / BS, c = i % BS;
            int gy = oy0 + r - HALO, gx = ox0 + c - HALO;
            float v = 0.f;
            if (gy >= 0 && gy < H && gx >= 0 && gx < W) v = s[gy * W + gx];
            buf[r * BW + c] = v;
        }
    }
    __syncthreads();

#pragma unroll 1
    for (int pass = 0; pass < NP; ++pass) {
        int S = BS - 2 * pass * P;
        int wOut = S - 2 * P;
        int ncell = (wOut + 3) >> 2;
        int cellsH = S * ncell;
        for (int i = tid; i < cellsH; i += 512) {
            int r = i / ncell, cc = (i % ncell) * 4;
            const float* bp = &buf[r * BW + cc];
            float4 A = *(const float4*)bp;
            float4 Bv = *(const float4*)(bp + 4);
            float o0, o1, o2, o3;
            if (P == 2) {
                float t = A.x + A.y + A.z + A.w + Bv.x;
                o0 = t;
                t += Bv.y - A.x; o1 = t;
                t += Bv.z - A.y; o2 = t;
                t += Bv.w - A.z; o3 = t;
            } else {
                float4 Cv = *(const float4*)(bp + 8);
                float t = A.x + A.y + A.z + A.w + Bv.x + Bv.y + Bv.z;
                o0 = t;
                t += Bv.w - A.x; o1 = t;
                t += Cv.x - A.y; o2 = t;
                t += Cv.y - A.z; o3 = t;
            }
            *(float4*)&tmp[r * BW + cc] =
                make_float4(o0 * inv, o1 * inv, o2 * inv, o3 * inv);
        }
        __syncthreads();
        int org = (pass + 1) * P;
        int cellsV = wOut * ncell;
        for (int i = tid; i < cellsV; i += 512) {
            int r = i / ncell, cc = (i % ncell) * 4;
            float4 acc = *(const float4*)&tmp[r * BW + cc];
#pragma unroll
            for (int j = 1; j <= 2 * P; ++j) {
                float4 v = *(const float4*)&tmp[(r + j) * BW + cc];
                acc.x += v.x; acc.y += v.y; acc.z += v.z; acc.w += v.w;
            }
            int gy = oy0 - HALO + org + r;
            int gx = ox0 - HALO + org + cc;
            bool ry = (gy >= 0 && gy < H);
            float4 o;
            o.x = (ry && gx >= 0 && gx < W) ? acc.x * inv : 0.f;
            o.y = (ry && gx + 1 >= 0 && gx + 1 < W) ? acc.y * inv : 0.f;
            o.z = (ry && gx + 2 >= 0 && gx + 2 < W) ? acc.z * inv : 0.f;
            o.w = (ry && gx + 3 >= 0 && gx + 3 < W) ? acc.w * inv : 0.f;
            *(float4*)&buf[r * BW + cc] = o;
        }
        __syncthreads();
    }

    float* d = dst + (size_t)b * HW;
    for (int i = tid; i < T * (T / 4); i += 512) {
        int r = i / (T / 4), cc = (i % (T / 4)) * 4;
        *(float4*)&d[(size_t)(oy0 + r) * W + ox0 + cc] =
            *(const float4*)&buf[r * BW + cc];
    }
}

// ---------------- grid-parallel exact top-k ----------------

__global__ __launch_bounds__(256) void zero_kernel(unsigned* __restrict__ hist,
                                                   int* __restrict__ meta,
                                                   int nh, int nmeta) {
    int i = blockIdx.x * blockDim.x + threadIdx.x;
    if (i < nh) hist[i] = 0;
    if (i < nmeta) meta[i] = 0;
}

__global__ __launch_bounds__(256) void hist_kernel(
    const float* __restrict__ map, unsigned* __restrict__ hist) {
    __shared__ unsigned lh[HBINS];
    int b = blockIdx.x / SLICES, sl = blockIdx.x % SLICES;
    for (int i = threadIdx.x; i < HBINS; i += 256) lh[i] = 0;
    __syncthreads();
    const unsigned* u = (const unsigned*)(map + (size_t)b * HW);
    int per = HW / SLICES;  // 6272
    int start = sl * per;
    for (int i = start + threadIdx.x; i < start + per; i += 256)
        atomicAdd(&lh[u[i] >> HSHIFT], 1u);
    __syncthreads();
    unsigned* gh = hist + (size_t)b * HBINS;
    for (int i = threadIdx.x; i < HBINS; i += 256) {
        unsigned c = lh[i];
        if (c) atomicAdd(&gh[i], c);
    }
}

__global__ __launch_bounds__(256) void select_kernel(
    const unsigned* __restrict__ hist, int* __restrict__ selbin) {
    int b = blockIdx.x;
    const unsigned* gh = hist + (size_t)b * HBINS;
    constexpr int CHUNK = HBINS / 256;  // 32
    __shared__ unsigned csum[256];
    int tid = threadIdx.x;
    unsigned s = 0;
#pragma unroll
    for (int j = 0; j < CHUNK; ++j) s += gh[tid * CHUNK + j];
    csum[tid] = s;
    __syncthreads();
    if (tid == 0) {
        unsigned acc = 0;
        int t = 255;
        for (; t > 0; --t) {
            if (acc + csum[t] >= TOPK) break;
            acc += csum[t];
        }
        int base = t * CHUNK;
        int j = CHUNK - 1;
        for (; j > 0; --j) {
            unsigned c = gh[base + j];
            if (acc + c >= TOPK) break;
            acc += c;
        }
        selbin[b * CSTRIDE] = base + j;
    }
}

__global__ __launch_bounds__(256) void compact_kernel(
    const float* __restrict__ map, const int* __restrict__ selbin,
    int* __restrict__ ccount, float* __restrict__ cand) {
    int tid = threadIdx.x;
    size_t base = (size_t)blockIdx.x * 1024;
    int b = (int)(base / HW);
    int sb = selbin[b * CSTRIDE];
    const uint4* u4 = (const uint4*)(((const unsigned*)map) + base);
    uint4 v = u4[tid];
    unsigned take0 = ((int)(v.x >> HSHIFT) >= sb);
    unsigned take1 = ((int)(v.y >> HSHIFT) >= sb);
    unsigned take2 = ((int)(v.z >> HSHIFT) >= sb);
    unsigned take3 = ((int)(v.w >> HSHIFT) >= sb);
    int c = (int)(take0 + take1 + take2 + take3);

    __shared__ int blkcnt, blkbase;
    if (tid == 0) blkcnt = 0;
    __syncthreads();
    int pos = 0;
    if (c) pos = atomicAdd(&blkcnt, c);
    __syncthreads();
    if (tid == 0 && blkcnt > 0)
        blkbase = atomicAdd(&ccount[b * CSTRIDE], blkcnt);
    __syncthreads();
    if (c) {
        float* o = cand + (size_t)b * HW + blkbase + pos;
        if (take0) *o++ = __uint_as_float(v.x);
        if (take1) *o++ = __uint_as_float(v.y);
        if (take2) *o++ = __uint_as_float(v.z);
        if (take3) *o = __uint_as_float(v.w);
    }
}

__global__ __launch_bounds__(256) void topk_kernel(
    const float* __restrict__ cand, const int* __restrict__ ccount,
    float* __restrict__ score) {
    int b = blockIdx.x;
    const float* s = cand + (size_t)b * HW;
    const unsigned* u = (const unsigned*)s;
    int M = ccount[b * CSTRIDE];
    __shared__ unsigned hist[256];
    __shared__ unsigned sh_prefix;
    __shared__ int sh_k;
    int tid = threadIdx.x;

    unsigned prefix = 0;
    int k = TOPK;
    for (int dgt = 3; dgt >= 0; --dgt) {
        hist[tid] = 0;
        __syncthreads();
        for (int i = tid; i < M; i += 256) {
            unsigned v = u[i];
            bool match;
            if (dgt == 3) match = true;
            else match = ((v >> (8 * (dgt + 1))) == prefix);
            if (match) atomicAdd(&hist[(v >> (8 * dgt)) & 255u], 1u);
        }
        __syncthreads();
        if (tid == 0) {
            int acc = 0;
            int j = 255;
            for (; j >= 0; --j) {
                acc += (int)hist[j];
                if (acc >= k) break;
            }
            sh_k = k - (acc - (int)hist[j]);
            sh_prefix = (prefix << 8) | (unsigned)j;
        }
        __syncthreads();
        prefix = sh_prefix;
        k = sh_k;
        __syncthreads();
    }

    float thr = __uint_as_float(prefix);
    float sum = 0.f;
    int cnt = 0;
    for (int i = tid; i < M; i += 256) {
        float v = s[i];
        if (v > thr) { sum += v; cnt++; }
    }
#pragma unroll
    for (int off = 32; off > 0; off >>= 1) {
        sum += __shfl_xor(sum, off);
        cnt += __shfl_xor(cnt, off);
    }
    __shared__ float wsum[4];
    __shared__ int wcnt[4];
    int wv = tid >> 6;
    if ((tid & 63) == 0) { wsum[wv] = sum; wcnt[wv] = cnt; }
    __syncthreads();
    if (tid == 0) {
        float s2 = 0.f;
        int c2 = 0;
        for (int i = 0; i < 4; ++i) { s2 += wsum[i]; c2 += wcnt[i]; }
        score[b] = (s2 + (float)(TOPK - c2) * thr) * (1.0f / TOPK);
    }
}

extern "C" void kernel_launch(void* const* d_in, const int* in_sizes, int n_in,
                              void* d_out, int out_size, void* d_ws, size_t ws_size,
                              hipStream_t stream) {
    const float* mid = (const float*)d_in[0];
    const float* last = (const float*)d_in[1];
    const float* pmid = (const float*)d_in[2];
    const float* plast = (const float*)d_in[3];
    int B = in_sizes[0] / (NPATCH * C);  // 16

    float* out_map = (float*)d_out;                   // B*448*448
    float* out_score = out_map + (size_t)B * HW;      // B

    float* combined = (float*)d_ws;
    int* meta = (int*)((char*)d_ws + 64 * 1024);
    int* ccount = meta;                               // [b*CSTRIDE]
    int* selbin = meta + 16 * CSTRIDE;                // [b*CSTRIDE]
    float* bufA = (float*)((char*)d_ws + 72 * 1024);  // B*HW floats
    unsigned* hist = (unsigned*)bufA;                 // overlays bufA
    float* cand = bufA;                               // overlays bufA

    int rows = B * NPATCH;
    anom_kernel<<<(rows + 3) / 4, 256, 0, stream>>>(mid, last, pmid, plast,
                                                    combined, rows);
    int nblk = B * 49;
    blur_fused_kernel<2, 5, true><<<nblk, 512, 0, stream>>>(combined, bufA);
    blur_fused_kernel<3, 3, false><<<nblk, 512, 0, stream>>>(bufA, out_map);

    int nh = B * HBINS;
    int nmeta = 2 * 16 * CSTRIDE;
    zero_kernel<<<(nh + 255) / 256, 256, 0, stream>>>(hist, meta, nh, nmeta);
    hist_kernel<<<B * SLICES, 256, 0, stream>>>(out_map, hist);
    select_kernel<<<B, 256, 0, stream>>>(hist, selbin);
    int nc = (B * HW) / 1024;
    compact_kernel<<<nc, 256, 0, stream>>>(out_map, selbin, ccount, cand);
    topk_kernel<<<B, 256, 0, stream>>>(cand, ccount, out_score);
}

// Round 6
// 164.334 us; speedup vs baseline: 4.7616x; 1.0137x over previous
//
#include <hip/hip_runtime.h>

constexpr int C = 768;
constexpr int NPATCH = 1024;   // (448/14)^2
constexpr int H = 448, W = 448;
constexpr int HW = H * W;      // 200704
constexpr int TOPK = 200;      // int(200704 * 0.001)
constexpr float EPS = 1e-12f;

constexpr int HBITS = 13;
constexpr int HBINS = 1 << HBITS;   // 8192
constexpr int HSHIFT = 18;          // bin = float_bits >> 18 (sign always 0)
constexpr int SLICES = 32;          // hist blocks per batch
constexpr int CSTRIDE = 64;         // ints between per-batch counters (256B)

typedef float f32x4 __attribute__((ext_vector_type(4)));

__device__ __forceinline__ float dotv(const f32x4 a, const f32x4 b) {
    return a.x * b.x + a.y * b.y + a.z * b.z + a.w * b.w;
}

// async global->LDS, 16B per lane, no VGPR destination (unlimited MLP)
__device__ __forceinline__ void gload_lds16(const float* g, float* lds) {
    __builtin_amdgcn_global_load_lds(
        (const __attribute__((address_space(1))) void*)g,
        (__attribute__((address_space(3))) void*)lds, 16, 0, 0);
}

// One wave per (b,n) row. Stage row (4 arrays x 3KB) into a wave-private
// 12KB LDS slice via global_load_lds (no VGPR dest -> all 12 loads in
// flight), then reduce from LDS. No __syncthreads needed (wave-local).
__global__ __launch_bounds__(256) void anom_kernel(
    const float* __restrict__ m, const float* __restrict__ l,
    const float* __restrict__ pm, const float* __restrict__ pl,
    float* __restrict__ combined, int rows) {
    __shared__ float lds[4][4][768];  // [wave][array][elem] = 48KB
    int w = threadIdx.x >> 6;
    int lane = threadIdx.x & 63;
    int wid = blockIdx.x * 4 + w;
    if (wid >= rows) return;
    size_t rowoff = (size_t)wid * C;
    const float* g0 = m + rowoff;
    const float* g1 = pm + rowoff;
    const float* g2 = l + rowoff;
    const float* g3 = pl + rowoff;
    int lo = lane * 4;

#pragma unroll
    for (int j = 0; j < 3; ++j)
        gload_lds16(g0 + j * 256 + lo, &lds[w][0][j * 256 + lo]);
#pragma unroll
    for (int j = 0; j < 3; ++j)
        gload_lds16(g1 + j * 256 + lo, &lds[w][1][j * 256 + lo]);
#pragma unroll
    for (int j = 0; j < 3; ++j)
        gload_lds16(g2 + j * 256 + lo, &lds[w][2][j * 256 + lo]);
#pragma unroll
    for (int j = 0; j < 3; ++j)
        gload_lds16(g3 + j * 256 + lo, &lds[w][3][j * 256 + lo]);

    asm volatile("s_waitcnt vmcnt(0)" ::: "memory");

    float mm = 0.f, pp = 0.f, mp = 0.f, ll = 0.f, qq = 0.f, lq = 0.f;
#pragma unroll
    for (int j = 0; j < 3; ++j) {
        f32x4 a = *(const f32x4*)&lds[w][0][j * 256 + lo];
        f32x4 b = *(const f32x4*)&lds[w][1][j * 256 + lo];
        f32x4 c = *(const f32x4*)&lds[w][2][j * 256 + lo];
        f32x4 d = *(const f32x4*)&lds[w][3][j * 256 + lo];
        mm += dotv(a, a);
        pp += dotv(b, b);
        mp += dotv(a, b);
        ll += dotv(c, c);
        qq += dotv(d, d);
        lq += dotv(c, d);
    }

#pragma unroll
    for (int off = 32; off > 0; off >>= 1) {
        mm += __shfl_xor(mm, off);
        pp += __shfl_xor(pp, off);
        mp += __shfl_xor(mp, off);
        ll += __shfl_xor(ll, off);
        qq += __shfl_xor(qq, off);
        lq += __shfl_xor(lq, off);
    }
    if (lane == 0) {
        float rm = 1.0f / fmaxf(sqrtf(mm), EPS);
        float rp = 1.0f / fmaxf(sqrtf(pp), EPS);
        float rl = 1.0f / fmaxf(sqrtf(ll), EPS);
        float rq = 1.0f / fmaxf(sqrtf(qq), EPS);
        float d2m = fmaxf(mm * rm * rm - 2.f * mp * rm * rp + pp * rp * rp, 0.f);
        float d2l = fmaxf(ll * rl * rl - 2.f * lq * rl * rq + qq * rq * rq, 0.f);
        combined[wid] = sqrtf(d2m) * sqrtf(d2l);
    }
}

__device__ __forceinline__ float bilerp32(const float* __restrict__ s,
                                          int gy, int gx) {
    float sx = (gx + 0.5f) * (1.0f / 14.0f) - 0.5f;
    float sy = (gy + 0.5f) * (1.0f / 14.0f) - 0.5f;
    float fx0 = floorf(sx), fy0 = floorf(sy);
    float fx = sx - fx0, fy = sy - fy0;
    int x0 = (int)fx0, y0 = (int)fy0;
    int x0c = min(max(x0, 0), 31);
    int x1c = min(max(x0 + 1, 0), 31);
    int y0c = min(max(y0, 0), 31);
    int y1c = min(max(y0 + 1, 0), 31);
    float v00 = s[y0c * 32 + x0c], v01 = s[y0c * 32 + x1c];
    float v10 = s[y1c * 32 + x0c], v11 = s[y1c * 32 + x1c];
    return (1.f - fy) * ((1.f - fx) * v00 + fx * v01) +
           fy * ((1.f - fx) * v10 + fx * v11);
}

// Fused NP passes of (2P+1)^2 zero-padded box blur, 64x64 output tile,
// sliding-origin LDS scheme; all LDS access is b128.
template <int P, int NP, bool UPS>
__global__ __launch_bounds__(512) void blur_fused_kernel(
    const float* __restrict__ src, float* __restrict__ dst) {
    constexpr int T = 64;
    constexpr int HALO = NP * P;
    constexpr int BS = T + 2 * HALO;   // 84 (P2) / 82 (P3)
    constexpr int BW = 84;             // row stride (words), mult of 4
    constexpr float inv = 1.0f / (2 * P + 1);
    __shared__ float buf[BS * BW];
    __shared__ float tmp[84 * BW];

    int tilex = blockIdx.x % 7;
    int tiley = (blockIdx.x / 7) % 7;
    int b = blockIdx.x / 49;
    int ox0 = tilex * T, oy0 = tiley * T;
    int tid = threadIdx.x;

    if (UPS) {
        const float* s = src + (size_t)b * NPATCH;
        for (int i = tid; i < NPATCH; i += 512) tmp[i] = s[i];
        __syncthreads();
        for (int i = tid; i < BS * BS; i += 512) {
            int r = i / BS, c = i % BS;
            int gy = oy0 + r - HALO, gx = ox0 + c - HALO;
            float v = 0.f;
            if (gy >= 0 && gy < H && gx >= 0 && gx < W) v = bilerp32(tmp, gy, gx);
            buf[r * BW + c] = v;
        }
    } else {
        const float* s = src + (size_t)b * HW;
        for (int i = tid; i < BS * BS; i += 512) {
            int r = i / BS, c = i % BS;
            int gy = oy0 + r - HALO, gx = ox0 + c - HALO;
            float v = 0.f;
            if (gy >= 0 && gy < H && gx >= 0 && gx < W) v = s[gy * W + gx];
            buf[r * BW + c] = v;
        }
    }
    __syncthreads();

#pragma unroll 1
    for (int pass = 0; pass < NP; ++pass) {
        int S = BS - 2 * pass * P;
        int wOut = S - 2 * P;
        int ncell = (wOut + 3) >> 2;
        int cellsH = S * ncell;
        for (int i = tid; i < cellsH; i += 512) {
            int r = i / ncell, cc = (i % ncell) * 4;
            const float* bp = &buf[r * BW + cc];
            float4 A = *(const float4*)bp;
            float4 Bv = *(const float4*)(bp + 4);
            float o0, o1, o2, o3;
            if (P == 2) {
                float t = A.x + A.y + A.z + A.w + Bv.x;
                o0 = t;
                t += Bv.y - A.x; o1 = t;
                t += Bv.z - A.y; o2 = t;
                t += Bv.w - A.z; o3 = t;
            } else {
                float4 Cv = *(const float4*)(bp + 8);
                float t = A.x + A.y + A.z + A.w + Bv.x + Bv.y + Bv.z;
                o0 = t;
                t += Bv.w - A.x; o1 = t;
                t += Cv.x - A.y; o2 = t;
                t += Cv.y - A.z; o3 = t;
            }
            *(float4*)&tmp[r * BW + cc] =
                make_float4(o0 * inv, o1 * inv, o2 * inv, o3 * inv);
        }
        __syncthreads();
        int org = (pass + 1) * P;
        int cellsV = wOut * ncell;
        for (int i = tid; i < cellsV; i += 512) {
            int r = i / ncell, cc = (i % ncell) * 4;
            float4 acc = *(const float4*)&tmp[r * BW + cc];
#pragma unroll
            for (int j = 1; j <= 2 * P; ++j) {
                float4 v = *(const float4*)&tmp[(r + j) * BW + cc];
                acc.x += v.x; acc.y += v.y; acc.z += v.z; acc.w += v.w;
            }
            int gy = oy0 - HALO + org + r;
            int gx = ox0 - HALO + org + cc;
            bool ry = (gy >= 0 && gy < H);
            float4 o;
            o.x = (ry && gx >= 0 && gx < W) ? acc.x * inv : 0.f;
            o.y = (ry && gx + 1 >= 0 && gx + 1 < W) ? acc.y * inv : 0.f;
            o.z = (ry && gx + 2 >= 0 && gx + 2 < W) ? acc.z * inv : 0.f;
            o.w = (ry && gx + 3 >= 0 && gx + 3 < W) ? acc.w * inv : 0.f;
            *(float4*)&buf[r * BW + cc] = o;
        }
        __syncthreads();
    }

    float* d = dst + (size_t)b * HW;
    for (int i = tid; i < T * (T / 4); i += 512) {
        int r = i / (T / 4), cc = (i % (T / 4)) * 4;
        *(float4*)&d[(size_t)(oy0 + r) * W + ox0 + cc] =
            *(const float4*)&buf[r * BW + cc];
    }
}

// ---------------- grid-parallel exact top-k ----------------

__global__ __launch_bounds__(256) void zero_kernel(unsigned* __restrict__ hist,
                                                   int* __restrict__ meta,
                                                   int nh, int nmeta) {
    int i = blockIdx.x * blockDim.x + threadIdx.x;
    if (i < nh) hist[i] = 0;
    if (i < nmeta) meta[i] = 0;
}

__global__ __launch_bounds__(256) void hist_kernel(
    const float* __restrict__ map, unsigned* __restrict__ hist) {
    __shared__ unsigned lh[HBINS];
    int b = blockIdx.x / SLICES, sl = blockIdx.x % SLICES;
    for (int i = threadIdx.x; i < HBINS; i += 256) lh[i] = 0;
    __syncthreads();
    const uint4* u4 = (const uint4*)(map + (size_t)b * HW);
    int per4 = HW / SLICES / 4;  // 1568
    int start = sl * per4;
    for (int i = start + threadIdx.x; i < start + per4; i += 256) {
        uint4 v = u4[i];
        atomicAdd(&lh[v.x >> HSHIFT], 1u);
        atomicAdd(&lh[v.y >> HSHIFT], 1u);
        atomicAdd(&lh[v.z >> HSHIFT], 1u);
        atomicAdd(&lh[v.w >> HSHIFT], 1u);
    }
    __syncthreads();
    unsigned* gh = hist + (size_t)b * HBINS;
    for (int i = threadIdx.x; i < HBINS; i += 256) {
        unsigned c = lh[i];
        if (c) atomicAdd(&gh[i], c);
    }
}

__global__ __launch_bounds__(256) void select_kernel(
    const unsigned* __restrict__ hist, int* __restrict__ selbin) {
    int b = blockIdx.x;
    const unsigned* gh = hist + (size_t)b * HBINS;
    constexpr int CHUNK = HBINS / 256;  // 32
    __shared__ unsigned csum[256];
    int tid = threadIdx.x;
    unsigned s = 0;
#pragma unroll
    for (int j = 0; j < CHUNK; ++j) s += gh[tid * CHUNK + j];
    csum[tid] = s;
    __syncthreads();
    if (tid == 0) {
        unsigned acc = 0;
        int t = 255;
        for (; t > 0; --t) {
            if (acc + csum[t] >= TOPK) break;
            acc += csum[t];
        }
        int base = t * CHUNK;
        int j = CHUNK - 1;
        for (; j > 0; --j) {
            unsigned c = gh[base + j];
            if (acc + c >= TOPK) break;
            acc += c;
        }
        selbin[b * CSTRIDE] = base + j;
    }
}

__global__ __launch_bounds__(256) void compact_kernel(
    const float* __restrict__ map, const int* __restrict__ selbin,
    int* __restrict__ ccount, float* __restrict__ cand) {
    int tid = threadIdx.x;
    size_t base = (size_t)blockIdx.x * 1024;
    int b = (int)(base / HW);
    int sb = selbin[b * CSTRIDE];
    const uint4* u4 = (const uint4*)(((const unsigned*)map) + base);
    uint4 v = u4[tid];
    unsigned take0 = ((int)(v.x >> HSHIFT) >= sb);
    unsigned take1 = ((int)(v.y >> HSHIFT) >= sb);
    unsigned take2 = ((int)(v.z >> HSHIFT) >= sb);
    unsigned take3 = ((int)(v.w >> HSHIFT) >= sb);
    int c = (int)(take0 + take1 + take2 + take3);

    __shared__ int blkcnt, blkbase;
    if (tid == 0) blkcnt = 0;
    __syncthreads();
    int pos = 0;
    if (c) pos = atomicAdd(&blkcnt, c);
    __syncthreads();
    if (tid == 0 && blkcnt > 0)
        blkbase = atomicAdd(&ccount[b * CSTRIDE], blkcnt);
    __syncthreads();
    if (c) {
        float* o = cand + (size_t)b * HW + blkbase + pos;
        if (take0) *o++ = __uint_as_float(v.x);
        if (take1) *o++ = __uint_as_float(v.y);
        if (take2) *o++ = __uint_as_float(v.z);
        if (take3) *o = __uint_as_float(v.w);
    }
}

__global__ __launch_bounds__(256) void topk_kernel(
    const float* __restrict__ cand, const int* __restrict__ ccount,
    float* __restrict__ score) {
    int b = blockIdx.x;
    const float* s = cand + (size_t)b * HW;
    const unsigned* u = (const unsigned*)s;
    int M = ccount[b * CSTRIDE];
    __shared__ unsigned hist[256];
    __shared__ unsigned sh_prefix;
    __shared__ int sh_k;
    int tid = threadIdx.x;

    unsigned prefix = 0;
    int k = TOPK;
    for (int dgt = 3; dgt >= 0; --dgt) {
        hist[tid] = 0;
        __syncthreads();
        for (int i = tid; i < M; i += 256) {
            unsigned v = u[i];
            bool match;
            if (dgt == 3) match = true;
            else match = ((v >> (8 * (dgt + 1))) == prefix);
            if (match) atomicAdd(&hist[(v >> (8 * dgt)) & 255u], 1u);
        }
        __syncthreads();
        if (tid == 0) {
            int acc = 0;
            int j = 255;
            for (; j >= 0; --j) {
                acc += (int)hist[j];
                if (acc >= k) break;
            }
            sh_k = k - (acc - (int)hist[j]);
            sh_prefix = (prefix << 8) | (unsigned)j;
        }
        __syncthreads();
        prefix = sh_prefix;
        k = sh_k;
        __syncthreads();
    }

    float thr = __uint_as_float(prefix);
    float sum = 0.f;
    int cnt = 0;
    for (int i = tid; i < M; i += 256) {
        float v = s[i];
        if (v > thr) { sum += v; cnt++; }
    }
#pragma unroll
    for (int off = 32; off > 0; off >>= 1) {
        sum += __shfl_xor(sum, off);
        cnt += __shfl_xor(cnt, off);
    }
    __shared__ float wsum[4];
    __shared__ int wcnt[4];
    int wv = tid >> 6;
    if ((tid & 63) == 0) { wsum[wv] = sum; wcnt[wv] = cnt; }
    __syncthreads();
    if (tid == 0) {
        float s2 = 0.f;
        int c2 = 0;
        for (int i = 0; i < 4; ++i) { s2 += wsum[i]; c2 += wcnt[i]; }
        score[b] = (s2 + (float)(TOPK - c2) * thr) * (1.0f / TOPK);
    }
}

extern "C" void kernel_launch(void* const* d_in, const int* in_sizes, int n_in,
                              void* d_out, int out_size, void* d_ws, size_t ws_size,
                              hipStream_t stream) {
    const float* mid = (const float*)d_in[0];
    const float* last = (const float*)d_in[1];
    const float* pmid = (const float*)d_in[2];
    const float* plast = (const float*)d_in[3];
    int B = in_sizes[0] / (NPATCH * C);  // 16

    float* out_map = (float*)d_out;                   // B*448*448
    float* out_score = out_map + (size_t)B * HW;      // B

    float* combined = (float*)d_ws;
    int* meta = (int*)((char*)d_ws + 64 * 1024);
    int* ccount = meta;                               // [b*CSTRIDE]
    int* selbin = meta + 16 * CSTRIDE;                // [b*CSTRIDE]
    float* bufA = (float*)((char*)d_ws + 72 * 1024);  // B*HW floats
    unsigned* hist = (unsigned*)bufA;                 // overlays bufA
    float* cand = bufA;                               // overlays bufA

    int rows = B * NPATCH;
    anom_kernel<<<(rows + 3) / 4, 256, 0, stream>>>(mid, last, pmid, plast,
                                                    combined, rows);
    int nblk = B * 49;
    blur_fused_kernel<2, 5, true><<<nblk, 512, 0, stream>>>(combined, bufA);
    blur_fused_kernel<3, 3, false><<<nblk, 512, 0, stream>>>(bufA, out_map);

    int nh = B * HBINS;
    int nmeta = 2 * 16 * CSTRIDE;
    zero_kernel<<<(nh + 255) / 256, 256, 0, stream>>>(hist, meta, nh, nmeta);
    hist_kernel<<<B * SLICES, 256, 0, stream>>>(out_map, hist);
    select_kernel<<<B, 256, 0, stream>>>(hist, selbin);
    int nc = (B * HW) / 1024;
    compact_kernel<<<nc, 256, 0, stream>>>(out_map, selbin, ccount, cand);
    topk_kernel<<<B, 256, 0, stream>>>(cand, ccount, out_score);
}